// Round 2
// baseline (254.649 us; speedup 1.0000x reference)
//
#include <hip/hip_runtime.h>
#include <hip/hip_bf16.h>

typedef __bf16 bf16x8 __attribute__((ext_vector_type(8)));
typedef __bf16 bf16x4 __attribute__((ext_vector_type(4)));
typedef float  f32x4  __attribute__((ext_vector_type(4)));

constexpr int SEQ = 2048;
constexpr int HD  = 64;    // head dim
constexpr int KT  = 64;    // keys per tile
constexpr int QB  = 64;    // queries per block (4 waves x 16)
constexpr int LDP = 72;    // padded LDS row (bf16 elems) = 144B, 16B-aligned

__global__ __launch_bounds__(256)
void attn_fwd(const float* __restrict__ Q, const float* __restrict__ K,
              const float* __restrict__ V, const int* __restrict__ mask,
              float* __restrict__ out)
{
    __shared__ __bf16 Kl[KT][LDP];        // [key][d]
    __shared__ __bf16 Vl[HD][LDP];        // [d][key]  (transposed)
    __shared__ __bf16 Pl[4][16][LDP];     // per-wave P tile [q][key]

    const int tid = threadIdx.x;
    const int w   = tid >> 6;     // wave id 0..3
    const int l   = tid & 63;     // lane
    const int lo  = l & 15;
    const int hi  = l >> 4;

    const int bh = blockIdx.y;            // 0..31  (b*16+h)
    const int b  = bh >> 4;
    const size_t base = (size_t)bh * SEQ * HD;
    const int qbase = blockIdx.x * QB + w * 16;

    // ---- Q fragments (A operand): row = qbase+lo, k(d) = kh*32 + hi*8 + i
    bf16x8 qf[2];
    {
        const float* qp = Q + base + (size_t)(qbase + lo) * HD;
        #pragma unroll
        for (int kh = 0; kh < 2; ++kh) {
            const float4 a = *(const float4*)(qp + kh*32 + hi*8);
            const float4 c = *(const float4*)(qp + kh*32 + hi*8 + 4);
            bf16x8 f;
            f[0]=(__bf16)a.x; f[1]=(__bf16)a.y; f[2]=(__bf16)a.z; f[3]=(__bf16)a.w;
            f[4]=(__bf16)c.x; f[5]=(__bf16)c.y; f[6]=(__bf16)c.z; f[7]=(__bf16)c.w;
            qf[kh] = f;
        }
    }

    f32x4 acc[4] = {{0,0,0,0},{0,0,0,0},{0,0,0,0},{0,0,0,0}};
    float m_run[4], l_run[4];
    #pragma unroll
    for (int r = 0; r < 4; ++r) { m_run[r] = -INFINITY; l_run[r] = 0.f; }

    const int* maskp = mask + b * SEQ;

    for (int k0 = 0; k0 < SEQ; k0 += KT) {
        // ---- stage K tile: f32 -> bf16, [key][d]
        #pragma unroll
        for (int i = 0; i < 4; ++i) {
            int e4 = i * 256 + tid;           // 1024 float4s = 64x64 elems
            int key = e4 >> 4, d4 = (e4 & 15) * 4;
            float4 kv = *(const float4*)(K + base + (size_t)(k0 + key) * HD + d4);
            bf16x4 kb;
            kb[0]=(__bf16)kv.x; kb[1]=(__bf16)kv.y; kb[2]=(__bf16)kv.z; kb[3]=(__bf16)kv.w;
            *(bf16x4*)&Kl[key][d4] = kb;
        }
        // ---- stage V tile transposed: [d][key]
        #pragma unroll
        for (int i = 0; i < 4; ++i) {
            int e4 = i * 256 + tid;
            int key = e4 >> 4, d4 = (e4 & 15) * 4;
            float4 vv = *(const float4*)(V + base + (size_t)(k0 + key) * HD + d4);
            Vl[d4+0][key] = (__bf16)vv.x;
            Vl[d4+1][key] = (__bf16)vv.y;
            Vl[d4+2][key] = (__bf16)vv.z;
            Vl[d4+3][key] = (__bf16)vv.w;
        }
        __syncthreads();

        // ---- QK^T: 4 sub-tiles of 16 keys; C: row(q)=hi*4+r, col(key)=lo
        float sv[4][4];                       // [sub][reg]
        #pragma unroll
        for (int s = 0; s < 4; ++s) {
            f32x4 c = {0,0,0,0};
            bf16x8 kf0 = *(const bf16x8*)&Kl[s*16 + lo][hi*8];
            bf16x8 kf1 = *(const bf16x8*)&Kl[s*16 + lo][32 + hi*8];
            c = __builtin_amdgcn_mfma_f32_16x16x32_bf16(qf[0], kf0, c, 0, 0, 0);
            c = __builtin_amdgcn_mfma_f32_16x16x32_bf16(qf[1], kf1, c, 0, 0, 0);
            const int km = maskp[k0 + s*16 + lo];
            #pragma unroll
            for (int r = 0; r < 4; ++r)
                sv[s][r] = km ? (c[r] * 0.03125f) : -1e9f;
        }

        // ---- online softmax (per wave, rows hi*4+r)
        float tm[4];
        #pragma unroll
        for (int r = 0; r < 4; ++r)
            tm[r] = fmaxf(fmaxf(sv[0][r], sv[1][r]), fmaxf(sv[2][r], sv[3][r]));
        #pragma unroll
        for (int off = 1; off < 16; off <<= 1)
            #pragma unroll
            for (int r = 0; r < 4; ++r)
                tm[r] = fmaxf(tm[r], __shfl_xor(tm[r], off));

        float scl[4];
        #pragma unroll
        for (int r = 0; r < 4; ++r) {
            float mn = fmaxf(m_run[r], tm[r]);
            scl[r] = __expf(m_run[r] - mn);
            m_run[r] = mn;
        }
        float pv_[4][4], rs[4] = {0.f, 0.f, 0.f, 0.f};
        #pragma unroll
        for (int s = 0; s < 4; ++s)
            #pragma unroll
            for (int r = 0; r < 4; ++r) {
                float p = __expf(sv[s][r] - m_run[r]);
                pv_[s][r] = p;
                rs[r] += p;
            }
        #pragma unroll
        for (int off = 1; off < 16; off <<= 1)
            #pragma unroll
            for (int r = 0; r < 4; ++r)
                rs[r] += __shfl_xor(rs[r], off);
        #pragma unroll
        for (int r = 0; r < 4; ++r)
            l_run[r] = l_run[r] * scl[r] + rs[r];
        #pragma unroll
        for (int nt = 0; nt < 4; ++nt)
            #pragma unroll
            for (int r = 0; r < 4; ++r)
                acc[nt][r] *= scl[r];

        // ---- stage P (per-wave region; in-wave DS ordering, no barrier)
        #pragma unroll
        for (int s = 0; s < 4; ++s)
            #pragma unroll
            for (int r = 0; r < 4; ++r)
                Pl[w][hi*4 + r][s*16 + lo] = (__bf16)pv_[s][r];

        // ---- PV: A = P[q][key], B = V^T[d][key] read as [k=key][n=d]
        bf16x8 pa0 = *(const bf16x8*)&Pl[w][lo][hi*8];
        bf16x8 pa1 = *(const bf16x8*)&Pl[w][lo][32 + hi*8];
        #pragma unroll
        for (int nt = 0; nt < 4; ++nt) {
            bf16x8 v0 = *(const bf16x8*)&Vl[nt*16 + lo][hi*8];
            bf16x8 v1 = *(const bf16x8*)&Vl[nt*16 + lo][32 + hi*8];
            acc[nt] = __builtin_amdgcn_mfma_f32_16x16x32_bf16(pa0, v0, acc[nt], 0, 0, 0);
            acc[nt] = __builtin_amdgcn_mfma_f32_16x16x32_bf16(pa1, v1, acc[nt], 0, 0, 0);
        }
        __syncthreads();
    }

    // ---- epilogue
    float inv[4];
    #pragma unroll
    for (int r = 0; r < 4; ++r) inv[r] = 1.0f / l_run[r];
    float* op = out + base + (size_t)qbase * HD;
    #pragma unroll
    for (int nt = 0; nt < 4; ++nt)
        #pragma unroll
        for (int r = 0; r < 4; ++r)
            op[(size_t)(hi*4 + r) * HD + nt*16 + lo] = acc[nt][r] * inv[r];
}

extern "C" void kernel_launch(void* const* d_in, const int* in_sizes, int n_in,
                              void* d_out, int out_size, void* d_ws, size_t ws_size,
                              hipStream_t stream) {
    (void)in_sizes; (void)n_in; (void)out_size; (void)d_ws; (void)ws_size;
    const float* Q  = (const float*)d_in[0];
    const float* K  = (const float*)d_in[1];
    const float* V  = (const float*)d_in[2];
    const int* mask = (const int*)d_in[3];
    float* out      = (float*)d_out;

    dim3 grid(SEQ / QB, 32);   // 32 q-tiles x (B*H = 32)
    hipLaunchKernelGGL(attn_fwd, grid, dim3(256), 0, stream,
                       Q, K, V, mask, out);
}

// Round 3
// 217.092 us; speedup vs baseline: 1.1730x; 1.1730x over previous
//
#include <hip/hip_runtime.h>
#include <hip/hip_bf16.h>

typedef __bf16 bf16x8 __attribute__((ext_vector_type(8)));
typedef __bf16 bf16x4 __attribute__((ext_vector_type(4)));
typedef float  f32x4  __attribute__((ext_vector_type(4)));

typedef __attribute__((address_space(3))) void lds_void;
typedef __attribute__((address_space(1))) const void gbl_void;

constexpr int SEQ = 2048;
constexpr int HD  = 64;     // head dim
constexpr int KT  = 64;     // keys per tile
constexpr int QB  = 64;     // queries per block (4 waves x 16)
constexpr int NT  = SEQ / KT;   // 32 tiles
constexpr int LDP = 72;     // padded LDS row for P

// =====================================================================
// Prepass: K -> bf16, row-major [bh][key][d], 16B-granule XOR-swizzled
//          (phys granule = g ^ (key&7)) so the main kernel's strided
//          ds_read_b128 of K rows is bank-conflict-free.
//          V -> bf16 V^T per 64-key tile: [bh][t][d][key], granule
//          swizzled by d (phys gk = gk ^ (d&7)).
// =====================================================================
__global__ __launch_bounds__(256)
void prepass(const float* __restrict__ K, const float* __restrict__ V,
             __bf16* __restrict__ Kb, __bf16* __restrict__ Vb)
{
    const int t   = blockIdx.x;   // tile 0..31
    const int bh  = blockIdx.y;   // 0..31
    const int tid = threadIdx.x;
    const size_t base = (size_t)bh * SEQ * HD;

    // ---- K: 512 granules (64 key x 8 g), 2 per thread
    #pragma unroll
    for (int p = 0; p < 2; ++p) {
        int task = p * 256 + tid;
        int key  = task >> 3, g = task & 7;
        const float* src = K + base + (size_t)(t * 64 + key) * HD + g * 8;
        float4 a = *(const float4*)src;
        float4 c = *(const float4*)(src + 4);
        bf16x8 o;
        o[0]=(__bf16)a.x; o[1]=(__bf16)a.y; o[2]=(__bf16)a.z; o[3]=(__bf16)a.w;
        o[4]=(__bf16)c.x; o[5]=(__bf16)c.y; o[6]=(__bf16)c.z; o[7]=(__bf16)c.w;
        __bf16* dst = Kb + ((size_t)bh * SEQ + t * 64 + key) * HD
                         + (size_t)((g ^ (key & 7)) * 8);
        *(bf16x8*)dst = o;
    }
    // ---- V^T: 512 granules (64 d x 8 gk), 2 per thread
    #pragma unroll
    for (int p = 0; p < 2; ++p) {
        int task = p * 256 + tid;
        int d = task >> 3, gk = task & 7;
        const float* src = V + base + (size_t)(t * 64 + gk * 8) * HD + d;
        bf16x8 o;
        #pragma unroll
        for (int j = 0; j < 8; ++j) o[j] = (__bf16)src[j * HD];
        __bf16* dst = Vb + (((size_t)bh * NT + t) * 64 + d) * 64
                         + (size_t)((gk ^ (d & 7)) * 8);
        *(bf16x8*)dst = o;
    }
}

// =====================================================================
// Main: flash attention, bf16 MFMA, double-buffered global_load_lds
// staging of pre-converted K / V^T tiles.
// =====================================================================
__global__ __launch_bounds__(256)
void attn_fwd2(const float* __restrict__ Q, const __bf16* __restrict__ Kb,
               const __bf16* __restrict__ Vb, const int* __restrict__ mask,
               float* __restrict__ out)
{
    __shared__ __bf16 Kl[2][KT][HD];   // 8KB each buf, swizzle lives in data
    __shared__ __bf16 Vl[2][HD][KT];
    __shared__ __bf16 Pl[4][16][LDP];  // per-wave P tile

    const int tid = threadIdx.x;
    const int w   = tid >> 6;
    const int l   = tid & 63;
    const int lo  = l & 15;
    const int hi  = l >> 4;

    const int bh = blockIdx.y;
    const int b  = bh >> 4;
    const size_t base = (size_t)bh * SEQ * HD;
    const int qbase = blockIdx.x * QB + w * 16;

    // ---- Q fragments (A): row = qbase+lo, k(d) = kh*32 + hi*8 + i
    bf16x8 qf[2];
    {
        const float* qp = Q + base + (size_t)(qbase + lo) * HD;
        #pragma unroll
        for (int kh = 0; kh < 2; ++kh) {
            const float4 a = *(const float4*)(qp + kh*32 + hi*8);
            const float4 c = *(const float4*)(qp + kh*32 + hi*8 + 4);
            bf16x8 f;
            f[0]=(__bf16)a.x; f[1]=(__bf16)a.y; f[2]=(__bf16)a.z; f[3]=(__bf16)a.w;
            f[4]=(__bf16)c.x; f[5]=(__bf16)c.y; f[6]=(__bf16)c.z; f[7]=(__bf16)c.w;
            qf[kh] = f;
        }
    }

    f32x4 acc[4] = {{0,0,0,0},{0,0,0,0},{0,0,0,0},{0,0,0,0}};
    float m_run[4], l_run[4];
    #pragma unroll
    for (int r = 0; r < 4; ++r) { m_run[r] = -INFINITY; l_run[r] = 0.f; }

    const int* maskp = mask + b * SEQ;
    const __bf16* Ksrc = Kb + (size_t)bh * SEQ * HD;
    const __bf16* Vsrc = Vb + (size_t)bh * NT * (64 * 64);

    // stage one 64-key tile (K 8KB + V 8KB) via global_load_lds width 16
    auto stage = [&](int buf, int t) {
        const __bf16* kg = Ksrc + (size_t)t * 4096;
        const __bf16* vg = Vsrc + (size_t)t * 4096;
        #pragma unroll
        for (int r = 0; r < 2; ++r)
            __builtin_amdgcn_global_load_lds(
                (gbl_void*)(kg + (size_t)(r*256 + tid) * 8),
                (lds_void*)(&Kl[buf][0][0] + (r*256 + w*64) * 8), 16, 0, 0);
        #pragma unroll
        for (int r = 0; r < 2; ++r)
            __builtin_amdgcn_global_load_lds(
                (gbl_void*)(vg + (size_t)(r*256 + tid) * 8),
                (lds_void*)(&Vl[buf][0][0] + (r*256 + w*64) * 8), 16, 0, 0);
    };

    stage(0, 0);
    __syncthreads();   // drains vmcnt(0): tile 0 landed

    for (int t = 0; t < NT; ++t) {
        const int buf = t & 1;
        if (t + 1 < NT) stage(buf ^ 1, t + 1);   // prefetch under compute

        // ---- QK^T
        float sv[4][4];
        #pragma unroll
        for (int s = 0; s < 4; ++s) {
            f32x4 c = {0,0,0,0};
            const int key = s*16 + lo;
            const __bf16* krow = &Kl[buf][key][0];
            bf16x8 kf0 = *(const bf16x8*)(krow + ((hi     ^ (lo & 7)) * 8));
            bf16x8 kf1 = *(const bf16x8*)(krow + (((4+hi) ^ (lo & 7)) * 8));
            c = __builtin_amdgcn_mfma_f32_16x16x32_bf16(qf[0], kf0, c, 0, 0, 0);
            c = __builtin_amdgcn_mfma_f32_16x16x32_bf16(qf[1], kf1, c, 0, 0, 0);
            const int km = maskp[t*KT + s*16 + lo];
            #pragma unroll
            for (int r = 0; r < 4; ++r)
                sv[s][r] = km ? (c[r] * 0.03125f) : -1e9f;
        }

        // ---- online softmax (rows hi*4+r, 16-lane column groups)
        float tm[4];
        #pragma unroll
        for (int r = 0; r < 4; ++r)
            tm[r] = fmaxf(fmaxf(sv[0][r], sv[1][r]), fmaxf(sv[2][r], sv[3][r]));
        #pragma unroll
        for (int off = 1; off < 16; off <<= 1)
            #pragma unroll
            for (int r = 0; r < 4; ++r)
                tm[r] = fmaxf(tm[r], __shfl_xor(tm[r], off));

        float scl[4];
        #pragma unroll
        for (int r = 0; r < 4; ++r) {
            float mn = fmaxf(m_run[r], tm[r]);
            scl[r] = __expf(m_run[r] - mn);
            m_run[r] = mn;
        }
        float pv_[4][4], rs[4] = {0.f, 0.f, 0.f, 0.f};
        #pragma unroll
        for (int s = 0; s < 4; ++s)
            #pragma unroll
            for (int r = 0; r < 4; ++r) {
                float p = __expf(sv[s][r] - m_run[r]);
                pv_[s][r] = p;
                rs[r] += p;
            }
        #pragma unroll
        for (int off = 1; off < 16; off <<= 1)
            #pragma unroll
            for (int r = 0; r < 4; ++r)
                rs[r] += __shfl_xor(rs[r], off);
        #pragma unroll
        for (int r = 0; r < 4; ++r)
            l_run[r] = l_run[r] * scl[r] + rs[r];
        #pragma unroll
        for (int nt = 0; nt < 4; ++nt)
            #pragma unroll
            for (int r = 0; r < 4; ++r)
                acc[nt][r] *= scl[r];

        // ---- stage P (per-wave region; in-wave DS ordering)
        #pragma unroll
        for (int s = 0; s < 4; ++s)
            #pragma unroll
            for (int r = 0; r < 4; ++r)
                Pl[w][hi*4 + r][s*16 + lo] = (__bf16)pv_[s][r];

        // ---- PV: A = P[q][key], B = V^T[d][key] (swizzled granules)
        bf16x8 pa0 = *(const bf16x8*)&Pl[w][lo][hi*8];
        bf16x8 pa1 = *(const bf16x8*)&Pl[w][lo][32 + hi*8];
        #pragma unroll
        for (int nt = 0; nt < 4; ++nt) {
            const int d = nt*16 + lo;
            const __bf16* vrow = &Vl[buf][d][0];
            bf16x8 v0 = *(const bf16x8*)(vrow + ((hi     ^ (lo & 7)) * 8));
            bf16x8 v1 = *(const bf16x8*)(vrow + (((4+hi) ^ (lo & 7)) * 8));
            acc[nt] = __builtin_amdgcn_mfma_f32_16x16x32_bf16(pa0, v0, acc[nt], 0, 0, 0);
            acc[nt] = __builtin_amdgcn_mfma_f32_16x16x32_bf16(pa1, v1, acc[nt], 0, 0, 0);
        }
        __syncthreads();   // drains vmcnt: next tile landed; P/V reads done
    }

    // ---- epilogue
    float inv[4];
    #pragma unroll
    for (int r = 0; r < 4; ++r) inv[r] = 1.0f / l_run[r];
    float* op = out + base + (size_t)qbase * HD;
    #pragma unroll
    for (int nt = 0; nt < 4; ++nt)
        #pragma unroll
        for (int r = 0; r < 4; ++r)
            op[(size_t)(hi*4 + r) * HD + nt*16 + lo] = acc[nt][r] * inv[r];
}

// =====================================================================
// Legacy (round-2, passing) kernel: fallback if ws_size is too small.
// =====================================================================
__global__ __launch_bounds__(256)
void attn_fwd_legacy(const float* __restrict__ Q, const float* __restrict__ K,
                     const float* __restrict__ V, const int* __restrict__ mask,
                     float* __restrict__ out)
{
    __shared__ __bf16 Kl[KT][LDP];
    __shared__ __bf16 Vl[HD][LDP];
    __shared__ __bf16 Pl[4][16][LDP];

    const int tid = threadIdx.x;
    const int w   = tid >> 6;
    const int l   = tid & 63;
    const int lo  = l & 15;
    const int hi  = l >> 4;

    const int bh = blockIdx.y;
    const int b  = bh >> 4;
    const size_t base = (size_t)bh * SEQ * HD;
    const int qbase = blockIdx.x * QB + w * 16;

    bf16x8 qf[2];
    {
        const float* qp = Q + base + (size_t)(qbase + lo) * HD;
        #pragma unroll
        for (int kh = 0; kh < 2; ++kh) {
            const float4 a = *(const float4*)(qp + kh*32 + hi*8);
            const float4 c = *(const float4*)(qp + kh*32 + hi*8 + 4);
            bf16x8 f;
            f[0]=(__bf16)a.x; f[1]=(__bf16)a.y; f[2]=(__bf16)a.z; f[3]=(__bf16)a.w;
            f[4]=(__bf16)c.x; f[5]=(__bf16)c.y; f[6]=(__bf16)c.z; f[7]=(__bf16)c.w;
            qf[kh] = f;
        }
    }

    f32x4 acc[4] = {{0,0,0,0},{0,0,0,0},{0,0,0,0},{0,0,0,0}};
    float m_run[4], l_run[4];
    #pragma unroll
    for (int r = 0; r < 4; ++r) { m_run[r] = -INFINITY; l_run[r] = 0.f; }

    const int* maskp = mask + b * SEQ;

    for (int k0 = 0; k0 < SEQ; k0 += KT) {
        #pragma unroll
        for (int i = 0; i < 4; ++i) {
            int e4 = i * 256 + tid;
            int key = e4 >> 4, d4 = (e4 & 15) * 4;
            float4 kv = *(const float4*)(K + base + (size_t)(k0 + key) * HD + d4);
            bf16x4 kb;
            kb[0]=(__bf16)kv.x; kb[1]=(__bf16)kv.y; kb[2]=(__bf16)kv.z; kb[3]=(__bf16)kv.w;
            *(bf16x4*)&Kl[key][d4] = kb;
        }
        #pragma unroll
        for (int i = 0; i < 4; ++i) {
            int e4 = i * 256 + tid;
            int key = e4 >> 4, d4 = (e4 & 15) * 4;
            float4 vv = *(const float4*)(V + base + (size_t)(k0 + key) * HD + d4);
            Vl[d4+0][key] = (__bf16)vv.x;
            Vl[d4+1][key] = (__bf16)vv.y;
            Vl[d4+2][key] = (__bf16)vv.z;
            Vl[d4+3][key] = (__bf16)vv.w;
        }
        __syncthreads();

        float sv[4][4];
        #pragma unroll
        for (int s = 0; s < 4; ++s) {
            f32x4 c = {0,0,0,0};
            bf16x8 kf0 = *(const bf16x8*)&Kl[s*16 + lo][hi*8];
            bf16x8 kf1 = *(const bf16x8*)&Kl[s*16 + lo][32 + hi*8];
            c = __builtin_amdgcn_mfma_f32_16x16x32_bf16(qf[0], kf0, c, 0, 0, 0);
            c = __builtin_amdgcn_mfma_f32_16x16x32_bf16(qf[1], kf1, c, 0, 0, 0);
            const int km = maskp[k0 + s*16 + lo];
            #pragma unroll
            for (int r = 0; r < 4; ++r)
                sv[s][r] = km ? (c[r] * 0.03125f) : -1e9f;
        }

        float tm[4];
        #pragma unroll
        for (int r = 0; r < 4; ++r)
            tm[r] = fmaxf(fmaxf(sv[0][r], sv[1][r]), fmaxf(sv[2][r], sv[3][r]));
        #pragma unroll
        for (int off = 1; off < 16; off <<= 1)
            #pragma unroll
            for (int r = 0; r < 4; ++r)
                tm[r] = fmaxf(tm[r], __shfl_xor(tm[r], off));

        float scl[4];
        #pragma unroll
        for (int r = 0; r < 4; ++r) {
            float mn = fmaxf(m_run[r], tm[r]);
            scl[r] = __expf(m_run[r] - mn);
            m_run[r] = mn;
        }
        float pv_[4][4], rs[4] = {0.f, 0.f, 0.f, 0.f};
        #pragma unroll
        for (int s = 0; s < 4; ++s)
            #pragma unroll
            for (int r = 0; r < 4; ++r) {
                float p = __expf(sv[s][r] - m_run[r]);
                pv_[s][r] = p;
                rs[r] += p;
            }
        #pragma unroll
        for (int off = 1; off < 16; off <<= 1)
            #pragma unroll
            for (int r = 0; r < 4; ++r)
                rs[r] += __shfl_xor(rs[r], off);
        #pragma unroll
        for (int r = 0; r < 4; ++r)
            l_run[r] = l_run[r] * scl[r] + rs[r];
        #pragma unroll
        for (int nt = 0; nt < 4; ++nt)
            #pragma unroll
            for (int r = 0; r < 4; ++r)
                acc[nt][r] *= scl[r];

        #pragma unroll
        for (int s = 0; s < 4; ++s)
            #pragma unroll
            for (int r = 0; r < 4; ++r)
                Pl[w][hi*4 + r][s*16 + lo] = (__bf16)pv_[s][r];

        bf16x8 pa0 = *(const bf16x8*)&Pl[w][lo][hi*8];
        bf16x8 pa1 = *(const bf16x8*)&Pl[w][lo][32 + hi*8];
        #pragma unroll
        for (int nt = 0; nt < 4; ++nt) {
            bf16x8 v0 = *(const bf16x8*)&Vl[nt*16 + lo][hi*8];
            bf16x8 v1 = *(const bf16x8*)&Vl[nt*16 + lo][32 + hi*8];
            acc[nt] = __builtin_amdgcn_mfma_f32_16x16x32_bf16(pa0, v0, acc[nt], 0, 0, 0);
            acc[nt] = __builtin_amdgcn_mfma_f32_16x16x32_bf16(pa1, v1, acc[nt], 0, 0, 0);
        }
        __syncthreads();
    }

    float inv[4];
    #pragma unroll
    for (int r = 0; r < 4; ++r) inv[r] = 1.0f / l_run[r];
    float* op = out + base + (size_t)qbase * HD;
    #pragma unroll
    for (int nt = 0; nt < 4; ++nt)
        #pragma unroll
        for (int r = 0; r < 4; ++r)
            op[(size_t)(hi*4 + r) * HD + nt*16 + lo] = acc[nt][r] * inv[r];
}

extern "C" void kernel_launch(void* const* d_in, const int* in_sizes, int n_in,
                              void* d_out, int out_size, void* d_ws, size_t ws_size,
                              hipStream_t stream) {
    (void)in_sizes; (void)n_in; (void)out_size;
    const float* Q  = (const float*)d_in[0];
    const float* K  = (const float*)d_in[1];
    const float* V  = (const float*)d_in[2];
    const int* mask = (const int*)d_in[3];
    float* out      = (float*)d_out;

    const size_t kv_elems = (size_t)32 * SEQ * HD;          // per tensor
    const size_t need = kv_elems * 2 /*bf16*/ * 2 /*K+V*/;  // 16.78 MB

    if (ws_size >= need) {
        __bf16* Kb = (__bf16*)d_ws;
        __bf16* Vb = Kb + kv_elems;
        hipLaunchKernelGGL(prepass, dim3(NT, 32), dim3(256), 0, stream, K, V, Kb, Vb);
        hipLaunchKernelGGL(attn_fwd2, dim3(SEQ / QB, 32), dim3(256), 0, stream,
                           Q, Kb, Vb, mask, out);
    } else {
        hipLaunchKernelGGL(attn_fwd_legacy, dim3(SEQ / QB, 32), dim3(256), 0, stream,
                           Q, K, V, mask, out);
    }
}

// Round 4
// 168.724 us; speedup vs baseline: 1.5093x; 1.2867x over previous
//
#include <hip/hip_runtime.h>
#include <hip/hip_bf16.h>

typedef __bf16 bf16x8 __attribute__((ext_vector_type(8)));
typedef __bf16 bf16x4 __attribute__((ext_vector_type(4)));
typedef float  f32x4  __attribute__((ext_vector_type(4)));

constexpr int SEQ = 2048;
constexpr int HD  = 64;
constexpr int KT  = 64;
constexpr int QB  = 64;      // queries per block (4 waves x 16)
constexpr int NT  = SEQ / KT;   // 32 tiles
constexpr int LDP = 72;      // padded LDS row for P

// =====================================================================
// Prepass: rewrite K and V^T as bf16 in MFMA-FRAGMENT ORDER so the main
// kernel's fragment loads are single coalesced dwordx4 from L2.
//   Kf[bh][t][frag=s*2+kh][lane][8] : lane(lo,hi) = K[t*64+s*16+lo][kh*32+hi*8+i]
//   Vf[bh][t][frag=nt*2+kh][lane][8]: lane(lo,hi) = V[t*64+kh*32+hi*8+j][nt*16+lo]
// =====================================================================
__global__ __launch_bounds__(256)
void prepass(const float* __restrict__ K, const float* __restrict__ V,
             __bf16* __restrict__ Kf, __bf16* __restrict__ Vf)
{
    const int t = blockIdx.x, bh = blockIdx.y, tid = threadIdx.x;
    const size_t base = (size_t)bh * SEQ * HD;
    __bf16* kd = Kf + (size_t)(bh * NT + t) * 4096;
    __bf16* vd = Vf + (size_t)(bh * NT + t) * 4096;

    #pragma unroll
    for (int p = 0; p < 2; ++p) {
        int gran = p * 256 + tid;          // 0..511
        int frag = gran >> 6, l = gran & 63, lo = l & 15, hi = l >> 4;
        int s = frag >> 1, kh = frag & 1;
        const float* src = K + base + (size_t)(t*64 + s*16 + lo) * HD + kh*32 + hi*8;
        float4 a = *(const float4*)src, c = *(const float4*)(src + 4);
        bf16x8 o;
        o[0]=(__bf16)a.x; o[1]=(__bf16)a.y; o[2]=(__bf16)a.z; o[3]=(__bf16)a.w;
        o[4]=(__bf16)c.x; o[5]=(__bf16)c.y; o[6]=(__bf16)c.z; o[7]=(__bf16)c.w;
        *(bf16x8*)(kd + gran * 8) = o;
    }
    #pragma unroll
    for (int p = 0; p < 2; ++p) {
        int gran = p * 256 + tid;
        int frag = gran >> 6, l = gran & 63, lo = l & 15, hi = l >> 4;
        int nt = frag >> 1, kh = frag & 1;
        const float* src = V + base + (size_t)(t*64 + kh*32 + hi*8) * HD + nt*16 + lo;
        bf16x8 o;
        #pragma unroll
        for (int j = 0; j < 8; ++j) o[j] = (__bf16)src[j * HD];
        *(bf16x8*)(vd + gran * 8) = o;
    }
}

// =====================================================================
// Main: flash attention. No K/V LDS staging, no main-loop barriers.
// Swapped QK^T (A=K, B=Q) -> each lane owns one q-row; softmax reduce is
// in-lane tree + 2 shfls. Mask packed to 256B of LDS bits once per block.
// XCD-swizzled block id -> 4 heads per XCD (K+V bf16 = 2MB, L2-resident).
// =====================================================================
__global__ __launch_bounds__(256, 4)
void attn_fwd3(const float* __restrict__ Q, const __bf16* __restrict__ Kf,
               const __bf16* __restrict__ Vf, const int* __restrict__ mask,
               float* __restrict__ out)
{
    __shared__ __bf16 Pl[4][16][LDP];          // per-wave P tile [q][key]
    __shared__ unsigned long long Ml[NT];      // 2048 mask bits

    const int tid = threadIdx.x;
    const int w   = tid >> 6;
    const int l   = tid & 63;
    const int lo  = l & 15;
    const int hi  = l >> 4;

    const int id   = blockIdx.x;               // 0..1023
    const int virt = (id & 7) * 128 + (id >> 3);   // XCD-contiguous
    const int bh   = virt >> 5;                // 0..31
    const int qb   = virt & 31;
    const int b    = bh >> 4;
    const size_t base = (size_t)bh * SEQ * HD;
    const int qbase = qb * QB + w * 16;

    // ---- pack mask -> bits (8 keys/thread)
    {
        const int4* mp = (const int4*)(mask + b * SEQ);
        int4 m0 = mp[tid * 2], m1 = mp[tid * 2 + 1];
        unsigned byte =
            ((unsigned)(m0.x != 0)     ) | ((unsigned)(m0.y != 0) << 1) |
            ((unsigned)(m0.z != 0) << 2) | ((unsigned)(m0.w != 0) << 3) |
            ((unsigned)(m1.x != 0) << 4) | ((unsigned)(m1.y != 0) << 5) |
            ((unsigned)(m1.z != 0) << 6) | ((unsigned)(m1.w != 0) << 7);
        ((unsigned char*)Ml)[tid] = (unsigned char)byte;
    }

    // ---- Q fragments (B operand): q = qbase+lo, k(d) = kh*32 + hi*8 + i
    bf16x8 qf[2];
    {
        const float* qp = Q + base + (size_t)(qbase + lo) * HD;
        #pragma unroll
        for (int kh = 0; kh < 2; ++kh) {
            const float4 a = *(const float4*)(qp + kh*32 + hi*8);
            const float4 c = *(const float4*)(qp + kh*32 + hi*8 + 4);
            bf16x8 f;
            f[0]=(__bf16)a.x; f[1]=(__bf16)a.y; f[2]=(__bf16)a.z; f[3]=(__bf16)a.w;
            f[4]=(__bf16)c.x; f[5]=(__bf16)c.y; f[6]=(__bf16)c.z; f[7]=(__bf16)c.w;
            qf[kh] = f;
        }
    }

    __syncthreads();   // Ml ready (only barrier in the kernel)

    f32x4 acc[4] = {{0,0,0,0},{0,0,0,0},{0,0,0,0},{0,0,0,0}};
    float m_run = -INFINITY, l_run = 0.f;

    const __bf16* Kb = Kf + (size_t)bh * NT * 4096 + l * 8;
    const __bf16* Vb = Vf + (size_t)bh * NT * 4096 + l * 8;

    for (int t = 0; t < NT; ++t) {
        const __bf16* Kt = Kb + (size_t)t * 4096;
        const __bf16* Vt = Vb + (size_t)t * 4096;

        // ---- QK^T swapped: sv[s][r] = S^T[key=s*16+hi*4+r][q=lo]
        float sv[4][4];
        const unsigned long long mb = Ml[t];
        #pragma unroll
        for (int s = 0; s < 4; ++s) {
            bf16x8 k0 = *(const bf16x8*)(Kt + (s*2+0) * 512);
            bf16x8 k1 = *(const bf16x8*)(Kt + (s*2+1) * 512);
            f32x4 c = {0,0,0,0};
            c = __builtin_amdgcn_mfma_f32_16x16x32_bf16(k0, qf[0], c, 0, 0, 0);
            c = __builtin_amdgcn_mfma_f32_16x16x32_bf16(k1, qf[1], c, 0, 0, 0);
            const unsigned ms = (unsigned)(mb >> (s * 16));
            #pragma unroll
            for (int r = 0; r < 4; ++r)
                sv[s][r] = c[r] * 0.03125f +
                           (((ms >> (hi*4 + r)) & 1u) ? 0.f : -1e9f);
        }

        // ---- V fragment loads issued early (independent of softmax)
        bf16x8 vfr[8];
        #pragma unroll
        for (int f = 0; f < 8; ++f) vfr[f] = *(const bf16x8*)(Vt + f * 512);

        // ---- online softmax: lane owns row q=lo (replicated over 4 hi-lanes)
        float tmx[4], tsm[4];
        #pragma unroll
        for (int s = 0; s < 4; ++s)
            tmx[s] = fmaxf(fmaxf(sv[s][0], sv[s][1]), fmaxf(sv[s][2], sv[s][3]));
        float pm = fmaxf(fmaxf(tmx[0], tmx[1]), fmaxf(tmx[2], tmx[3]));
        pm = fmaxf(pm, __shfl_xor(pm, 16));
        pm = fmaxf(pm, __shfl_xor(pm, 32));

        const float mn  = fmaxf(m_run, pm);
        const float scl = __expf(m_run - mn);
        m_run = mn;

        float p[4][4];
        #pragma unroll
        for (int s = 0; s < 4; ++s) {
            #pragma unroll
            for (int r = 0; r < 4; ++r)
                p[s][r] = __expf(sv[s][r] - mn);
            tsm[s] = (p[s][0] + p[s][1]) + (p[s][2] + p[s][3]);
        }
        float rs = (tsm[0] + tsm[1]) + (tsm[2] + tsm[3]);
        rs += __shfl_xor(rs, 16);
        rs += __shfl_xor(rs, 32);
        l_run = l_run * scl + rs;

        #pragma unroll
        for (int nt = 0; nt < 4; ++nt)
            #pragma unroll
            for (int r = 0; r < 4; ++r)
                acc[nt][r] *= scl;

        // ---- P^T -> Pl[w][q=lo][key]  (per-wave, in-wave DS ordering)
        #pragma unroll
        for (int s = 0; s < 4; ++s)
            #pragma unroll
            for (int r = 0; r < 4; ++r)
                Pl[w][lo][s*16 + hi*4 + r] = (__bf16)p[s][r];

        // ---- PV: O^T = V^T · P^T ; A=V-frag, B=P-frag (k = hi*8+i)
        bf16x8 pa0 = *(const bf16x8*)&Pl[w][lo][hi * 8];
        bf16x8 pa1 = *(const bf16x8*)&Pl[w][lo][32 + hi * 8];
        #pragma unroll
        for (int nt = 0; nt < 4; ++nt) {
            acc[nt] = __builtin_amdgcn_mfma_f32_16x16x32_bf16(vfr[nt*2+0], pa0, acc[nt], 0, 0, 0);
            acc[nt] = __builtin_amdgcn_mfma_f32_16x16x32_bf16(vfr[nt*2+1], pa1, acc[nt], 0, 0, 0);
        }
    }

    // ---- epilogue: acc[nt][r] = O^T[d=nt*16+hi*4+r][q=lo]
    const float inv = 1.0f / l_run;
    float* op = out + base + (size_t)(qbase + lo) * HD;
    #pragma unroll
    for (int nt = 0; nt < 4; ++nt)
        #pragma unroll
        for (int r = 0; r < 4; ++r)
            op[nt*16 + hi*4 + r] = acc[nt][r] * inv;
}

// =====================================================================
// Fallback (round-2, passing) if ws_size is too small.
// =====================================================================
__global__ __launch_bounds__(256)
void attn_fwd_legacy(const float* __restrict__ Q, const float* __restrict__ K,
                     const float* __restrict__ V, const int* __restrict__ mask,
                     float* __restrict__ out)
{
    __shared__ __bf16 Kl[KT][LDP];
    __shared__ __bf16 Vl[HD][LDP];
    __shared__ __bf16 Pl[4][16][LDP];

    const int tid = threadIdx.x;
    const int w   = tid >> 6;
    const int l   = tid & 63;
    const int lo  = l & 15;
    const int hi  = l >> 4;

    const int bh = blockIdx.y;
    const int b  = bh >> 4;
    const size_t base = (size_t)bh * SEQ * HD;
    const int qbase = blockIdx.x * QB + w * 16;

    bf16x8 qf[2];
    {
        const float* qp = Q + base + (size_t)(qbase + lo) * HD;
        #pragma unroll
        for (int kh = 0; kh < 2; ++kh) {
            const float4 a = *(const float4*)(qp + kh*32 + hi*8);
            const float4 c = *(const float4*)(qp + kh*32 + hi*8 + 4);
            bf16x8 f;
            f[0]=(__bf16)a.x; f[1]=(__bf16)a.y; f[2]=(__bf16)a.z; f[3]=(__bf16)a.w;
            f[4]=(__bf16)c.x; f[5]=(__bf16)c.y; f[6]=(__bf16)c.z; f[7]=(__bf16)c.w;
            qf[kh] = f;
        }
    }

    f32x4 acc[4] = {{0,0,0,0},{0,0,0,0},{0,0,0,0},{0,0,0,0}};
    float m_run[4], l_run[4];
    #pragma unroll
    for (int r = 0; r < 4; ++r) { m_run[r] = -INFINITY; l_run[r] = 0.f; }

    const int* maskp = mask + b * SEQ;

    for (int k0 = 0; k0 < SEQ; k0 += KT) {
        #pragma unroll
        for (int i = 0; i < 4; ++i) {
            int e4 = i * 256 + tid;
            int key = e4 >> 4, d4 = (e4 & 15) * 4;
            float4 kv = *(const float4*)(K + base + (size_t)(k0 + key) * HD + d4);
            bf16x4 kb;
            kb[0]=(__bf16)kv.x; kb[1]=(__bf16)kv.y; kb[2]=(__bf16)kv.z; kb[3]=(__bf16)kv.w;
            *(bf16x4*)&Kl[key][d4] = kb;
        }
        #pragma unroll
        for (int i = 0; i < 4; ++i) {
            int e4 = i * 256 + tid;
            int key = e4 >> 4, d4 = (e4 & 15) * 4;
            float4 vv = *(const float4*)(V + base + (size_t)(k0 + key) * HD + d4);
            Vl[d4+0][key] = (__bf16)vv.x;
            Vl[d4+1][key] = (__bf16)vv.y;
            Vl[d4+2][key] = (__bf16)vv.z;
            Vl[d4+3][key] = (__bf16)vv.w;
        }
        __syncthreads();

        float sv[4][4];
        #pragma unroll
        for (int s = 0; s < 4; ++s) {
            f32x4 c = {0,0,0,0};
            bf16x8 kf0 = *(const bf16x8*)&Kl[s*16 + lo][hi*8];
            bf16x8 kf1 = *(const bf16x8*)&Kl[s*16 + lo][32 + hi*8];
            c = __builtin_amdgcn_mfma_f32_16x16x32_bf16(qf[0], kf0, c, 0, 0, 0);
            c = __builtin_amdgcn_mfma_f32_16x16x32_bf16(qf[1], kf1, c, 0, 0, 0);
            const int km = maskp[k0 + s*16 + lo];
            #pragma unroll
            for (int r = 0; r < 4; ++r)
                sv[s][r] = km ? (c[r] * 0.03125f) : -1e9f;
        }

        float tm[4];
        #pragma unroll
        for (int r = 0; r < 4; ++r)
            tm[r] = fmaxf(fmaxf(sv[0][r], sv[1][r]), fmaxf(sv[2][r], sv[3][r]));
        #pragma unroll
        for (int off = 1; off < 16; off <<= 1)
            #pragma unroll
            for (int r = 0; r < 4; ++r)
                tm[r] = fmaxf(tm[r], __shfl_xor(tm[r], off));

        float scl[4];
        #pragma unroll
        for (int r = 0; r < 4; ++r) {
            float mn = fmaxf(m_run[r], tm[r]);
            scl[r] = __expf(m_run[r] - mn);
            m_run[r] = mn;
        }
        float pv_[4][4], rs[4] = {0.f, 0.f, 0.f, 0.f};
        #pragma unroll
        for (int s = 0; s < 4; ++s)
            #pragma unroll
            for (int r = 0; r < 4; ++r) {
                float p = __expf(sv[s][r] - m_run[r]);
                pv_[s][r] = p;
                rs[r] += p;
            }
        #pragma unroll
        for (int off = 1; off < 16; off <<= 1)
            #pragma unroll
            for (int r = 0; r < 4; ++r)
                rs[r] += __shfl_xor(rs[r], off);
        #pragma unroll
        for (int r = 0; r < 4; ++r)
            l_run[r] = l_run[r] * scl[r] + rs[r];
        #pragma unroll
        for (int nt = 0; nt < 4; ++nt)
            #pragma unroll
            for (int r = 0; r < 4; ++r)
                acc[nt][r] *= scl[r];

        #pragma unroll
        for (int s = 0; s < 4; ++s)
            #pragma unroll
            for (int r = 0; r < 4; ++r)
                Pl[w][hi*4 + r][s*16 + lo] = (__bf16)pv_[s][r];

        bf16x8 pa0 = *(const bf16x8*)&Pl[w][lo][hi*8];
        bf16x8 pa1 = *(const bf16x8*)&Pl[w][lo][32 + hi*8];
        #pragma unroll
        for (int nt = 0; nt < 4; ++nt) {
            bf16x8 v0 = *(const bf16x8*)&Vl[nt*16 + lo][hi*8];
            bf16x8 v1 = *(const bf16x8*)&Vl[nt*16 + lo][32 + hi*8];
            acc[nt] = __builtin_amdgcn_mfma_f32_16x16x32_bf16(pa0, v0, acc[nt], 0, 0, 0);
            acc[nt] = __builtin_amdgcn_mfma_f32_16x16x32_bf16(pa1, v1, acc[nt], 0, 0, 0);
        }
        __syncthreads();
    }

    float inv[4];
    #pragma unroll
    for (int r = 0; r < 4; ++r) inv[r] = 1.0f / l_run[r];
    float* op = out + base + (size_t)qbase * HD;
    #pragma unroll
    for (int nt = 0; nt < 4; ++nt)
        #pragma unroll
        for (int r = 0; r < 4; ++r)
            op[(size_t)(hi*4 + r) * HD + nt*16 + lo] = acc[nt][r] * inv[r];
}

extern "C" void kernel_launch(void* const* d_in, const int* in_sizes, int n_in,
                              void* d_out, int out_size, void* d_ws, size_t ws_size,
                              hipStream_t stream) {
    (void)in_sizes; (void)n_in; (void)out_size;
    const float* Q  = (const float*)d_in[0];
    const float* K  = (const float*)d_in[1];
    const float* V  = (const float*)d_in[2];
    const int* mask = (const int*)d_in[3];
    float* out      = (float*)d_out;

    const size_t kv_elems = (size_t)32 * SEQ * HD;          // per tensor
    const size_t need = kv_elems * 2 /*bf16*/ * 2 /*K+V*/;  // 16.78 MB

    if (ws_size >= need) {
        __bf16* Kf = (__bf16*)d_ws;
        __bf16* Vf = Kf + kv_elems;
        hipLaunchKernelGGL(prepass, dim3(NT, 32), dim3(256), 0, stream, K, V, Kf, Vf);
        hipLaunchKernelGGL(attn_fwd3, dim3(1024), dim3(256), 0, stream,
                           Q, Kf, Vf, mask, out);
    } else {
        hipLaunchKernelGGL(attn_fwd_legacy, dim3(SEQ / QB, 32), dim3(256), 0, stream,
                           Q, K, V, mask, out);
    }
}

// Round 5
// 161.189 us; speedup vs baseline: 1.5798x; 1.0467x over previous
//
#include <hip/hip_runtime.h>
#include <hip/hip_bf16.h>

typedef __bf16 bf16x8 __attribute__((ext_vector_type(8)));
typedef __bf16 bf16x4 __attribute__((ext_vector_type(4)));
typedef float  f32x4  __attribute__((ext_vector_type(4)));

constexpr int SEQ = 2048;
constexpr int HD  = 64;
constexpr int KT  = 64;
constexpr int QB  = 64;      // queries per block (4 waves x 16)
constexpr int NT  = SEQ / KT;   // 32 tiles
constexpr int LDP = 72;      // padded LDS row for P

// =====================================================================
// Prepass: rewrite K and V^T as bf16 in MFMA-FRAGMENT ORDER.
// Coalesced float4 reads -> LDS (bf16) -> coalesced bf16x8 frag writes.
//   Kf[bh][t][frag=s*2+kh][lane][8] : lane(lo,hi) = K[t*64+s*16+lo][kh*32+hi*8+j]
//   Vf[bh][t][frag=nt*2+kh][lane][8]: lane(lo,hi) = V[t*64+kh*32+hi*8+j][nt*16+lo]
// =====================================================================
__global__ __launch_bounds__(256)
void prepass(const float* __restrict__ K, const float* __restrict__ V,
             __bf16* __restrict__ Kf, __bf16* __restrict__ Vf)
{
    __shared__ __bf16 Kt[64][72];   // 144B rows: 16B-aligned frag reads
    __shared__ __bf16 Vt[64][72];

    const int t = blockIdx.x, bh = blockIdx.y, tid = threadIdx.x;
    const size_t base = (size_t)bh * SEQ * HD + (size_t)t * 64 * HD;

    // ---- coalesced tile load (1024 float4 per tensor, 4 rounds)
    #pragma unroll
    for (int p = 0; p < 4; ++p) {
        int idx = p * 256 + tid;          // float4 index
        int row = idx >> 4, c4 = (idx & 15) * 4;
        float4 kv = *(const float4*)(K + base + row * HD + c4);
        bf16x4 kb;
        kb[0]=(__bf16)kv.x; kb[1]=(__bf16)kv.y; kb[2]=(__bf16)kv.z; kb[3]=(__bf16)kv.w;
        *(bf16x4*)&Kt[row][c4] = kb;
        float4 vv = *(const float4*)(V + base + row * HD + c4);
        bf16x4 vb;
        vb[0]=(__bf16)vv.x; vb[1]=(__bf16)vv.y; vb[2]=(__bf16)vv.z; vb[3]=(__bf16)vv.w;
        *(bf16x4*)&Vt[row][c4] = vb;
    }
    __syncthreads();

    // ---- fragment-order writes (coalesced 16B/thread)
    __bf16* kd = Kf + (size_t)(bh * NT + t) * 4096;
    __bf16* vd = Vf + (size_t)(bh * NT + t) * 4096;
    #pragma unroll
    for (int p = 0; p < 2; ++p) {
        int gran = p * 256 + tid;         // 0..511
        int frag = gran >> 6, l = gran & 63, lo = l & 15, hi = l >> 4;
        int s = frag >> 1, kh = frag & 1;
        bf16x8 ko = *(const bf16x8*)&Kt[s*16 + lo][kh*32 + hi*8];
        *(bf16x8*)(kd + gran * 8) = ko;
        bf16x8 vo;
        #pragma unroll
        for (int j = 0; j < 8; ++j)
            vo[j] = Vt[kh*32 + hi*8 + j][s*16 + lo];
        *(bf16x8*)(vd + gran * 8) = vo;
    }
}

// =====================================================================
// Main: flash attention, no main-loop barriers, swapped QK^T, T13
// defer-max with per-lane partial row sums, packed P stores, setprio.
// =====================================================================
__global__ __launch_bounds__(256, 4)
void attn_fwd3(const float* __restrict__ Q, const __bf16* __restrict__ Kf,
               const __bf16* __restrict__ Vf, const int* __restrict__ mask,
               float* __restrict__ out)
{
    __shared__ __bf16 Pl[4][16][LDP];          // per-wave P tile [q][key]
    __shared__ unsigned long long Ml[NT];      // 2048 mask bits

    const int tid = threadIdx.x;
    const int w   = tid >> 6;
    const int l   = tid & 63;
    const int lo  = l & 15;
    const int hi  = l >> 4;

    const int id   = blockIdx.x;                   // 0..1023
    const int virt = (id & 7) * 128 + (id >> 3);   // XCD-contiguous
    const int bh   = virt >> 5;
    const int qb   = virt & 31;
    const int b    = bh >> 4;
    const size_t base = (size_t)bh * SEQ * HD;
    const int qbase = qb * QB + w * 16;

    // ---- pack mask -> bits (8 keys/thread)
    {
        const int4* mp = (const int4*)(mask + b * SEQ);
        int4 m0 = mp[tid * 2], m1 = mp[tid * 2 + 1];
        unsigned byte =
            ((unsigned)(m0.x != 0)     ) | ((unsigned)(m0.y != 0) << 1) |
            ((unsigned)(m0.z != 0) << 2) | ((unsigned)(m0.w != 0) << 3) |
            ((unsigned)(m1.x != 0) << 4) | ((unsigned)(m1.y != 0) << 5) |
            ((unsigned)(m1.z != 0) << 6) | ((unsigned)(m1.w != 0) << 7);
        ((unsigned char*)Ml)[tid] = (unsigned char)byte;
    }

    // ---- Q fragments (B operand): q = qbase+lo, k(d) = kh*32 + hi*8 + i
    bf16x8 qf[2];
    {
        const float* qp = Q + base + (size_t)(qbase + lo) * HD;
        #pragma unroll
        for (int kh = 0; kh < 2; ++kh) {
            const float4 a = *(const float4*)(qp + kh*32 + hi*8);
            const float4 c = *(const float4*)(qp + kh*32 + hi*8 + 4);
            bf16x8 f;
            f[0]=(__bf16)a.x; f[1]=(__bf16)a.y; f[2]=(__bf16)a.z; f[3]=(__bf16)a.w;
            f[4]=(__bf16)c.x; f[5]=(__bf16)c.y; f[6]=(__bf16)c.z; f[7]=(__bf16)c.w;
            qf[kh] = f;
        }
    }

    __syncthreads();   // Ml ready (only barrier in the kernel)

    f32x4 acc[4] = {{0,0,0,0},{0,0,0,0},{0,0,0,0},{0,0,0,0}};
    float m_run  = -INFINITY;   // row-uniform running max
    float l_part = 0.f;         // PER-LANE partial row sum (reduced in epilogue)

    const __bf16* Kb = Kf + (size_t)bh * NT * 4096 + l * 8;
    const __bf16* Vb = Vf + (size_t)bh * NT * 4096 + l * 8;

    for (int t = 0; t < NT; ++t) {
        const __bf16* Kt = Kb + (size_t)t * 4096;
        const __bf16* Vt = Vb + (size_t)t * 4096;

        // ---- QK^T swapped: sv[s][r] = S^T[key=s*16+hi*4+r][q=lo]
        float sv[4][4];
        const unsigned long long mb = Ml[t];
        __builtin_amdgcn_s_setprio(1);
        #pragma unroll
        for (int s = 0; s < 4; ++s) {
            bf16x8 k0 = *(const bf16x8*)(Kt + (s*2+0) * 512);
            bf16x8 k1 = *(const bf16x8*)(Kt + (s*2+1) * 512);
            f32x4 c = {0,0,0,0};
            c = __builtin_amdgcn_mfma_f32_16x16x32_bf16(k0, qf[0], c, 0, 0, 0);
            c = __builtin_amdgcn_mfma_f32_16x16x32_bf16(k1, qf[1], c, 0, 0, 0);
            const unsigned ms = (unsigned)(mb >> (s * 16));
            #pragma unroll
            for (int r = 0; r < 4; ++r)
                sv[s][r] = c[r] * 0.03125f +
                           (((ms >> (hi*4 + r)) & 1u) ? 0.f : -1e9f);
        }
        __builtin_amdgcn_s_setprio(0);

        // ---- V fragment loads issued early (independent of softmax)
        bf16x8 vfr[8];
        #pragma unroll
        for (int f = 0; f < 8; ++f) vfr[f] = *(const bf16x8*)(Vt + f * 512);

        // ---- T13 defer-max: in-lane partial max, skip reduce+rescale if small
        float pm = sv[0][0];
        #pragma unroll
        for (int s = 0; s < 4; ++s)
            #pragma unroll
            for (int r = 0; r < 4; ++r)
                pm = fmaxf(pm, sv[s][r]);

        if (!__all(pm - m_run <= 8.0f)) {
            float pmr = pm;
            pmr = fmaxf(pmr, __shfl_xor(pmr, 16));
            pmr = fmaxf(pmr, __shfl_xor(pmr, 32));
            const float mn  = fmaxf(m_run, pmr);
            const float scl = __expf(m_run - mn);
            m_run = mn;
            l_part *= scl;
            #pragma unroll
            for (int nt = 0; nt < 4; ++nt)
                #pragma unroll
                for (int r = 0; r < 4; ++r)
                    acc[nt][r] *= scl;
        }

        // ---- P = exp(S - m_run), per-lane partial sum
        float p[4][4], ls = 0.f;
        #pragma unroll
        for (int s = 0; s < 4; ++s) {
            #pragma unroll
            for (int r = 0; r < 4; ++r) {
                p[s][r] = __expf(sv[s][r] - m_run);
                ls += p[s][r];
            }
        }
        l_part += ls;

        // ---- packed P^T store: 4x ds_write_b64 (cols s*16+hi*4+0..3)
        #pragma unroll
        for (int s = 0; s < 4; ++s) {
            bf16x4 pk;
            pk[0]=(__bf16)p[s][0]; pk[1]=(__bf16)p[s][1];
            pk[2]=(__bf16)p[s][2]; pk[3]=(__bf16)p[s][3];
            *(bf16x4*)&Pl[w][lo][s*16 + hi*4] = pk;
        }

        // ---- PV: O^T = V^T · P^T ; A=V-frag, B=P-frag (k = hi*8+i)
        bf16x8 pa0 = *(const bf16x8*)&Pl[w][lo][hi * 8];
        bf16x8 pa1 = *(const bf16x8*)&Pl[w][lo][32 + hi * 8];
        __builtin_amdgcn_s_setprio(1);
        #pragma unroll
        for (int nt = 0; nt < 4; ++nt) {
            acc[nt] = __builtin_amdgcn_mfma_f32_16x16x32_bf16(vfr[nt*2+0], pa0, acc[nt], 0, 0, 0);
            acc[nt] = __builtin_amdgcn_mfma_f32_16x16x32_bf16(vfr[nt*2+1], pa1, acc[nt], 0, 0, 0);
        }
        __builtin_amdgcn_s_setprio(0);
    }

    // ---- epilogue: reduce per-lane partial sums across hi groups
    float lr = l_part;
    lr += __shfl_xor(lr, 16);
    lr += __shfl_xor(lr, 32);
    const float inv = 1.0f / lr;

    float* op = out + base + (size_t)(qbase + lo) * HD;
    #pragma unroll
    for (int nt = 0; nt < 4; ++nt)
        #pragma unroll
        for (int r = 0; r < 4; ++r)
            op[nt*16 + hi*4 + r] = acc[nt][r] * inv;
}

// =====================================================================
// Fallback (round-2, passing) if ws_size is too small.
// =====================================================================
__global__ __launch_bounds__(256)
void attn_fwd_legacy(const float* __restrict__ Q, const float* __restrict__ K,
                     const float* __restrict__ V, const int* __restrict__ mask,
                     float* __restrict__ out)
{
    __shared__ __bf16 Kl[KT][LDP];
    __shared__ __bf16 Vl[HD][LDP];
    __shared__ __bf16 Pl[4][16][LDP];

    const int tid = threadIdx.x;
    const int w   = tid >> 6;
    const int l   = tid & 63;
    const int lo  = l & 15;
    const int hi  = l >> 4;

    const int bh = blockIdx.y;
    const int b  = bh >> 4;
    const size_t base = (size_t)bh * SEQ * HD;
    const int qbase = blockIdx.x * QB + w * 16;

    bf16x8 qf[2];
    {
        const float* qp = Q + base + (size_t)(qbase + lo) * HD;
        #pragma unroll
        for (int kh = 0; kh < 2; ++kh) {
            const float4 a = *(const float4*)(qp + kh*32 + hi*8);
            const float4 c = *(const float4*)(qp + kh*32 + hi*8 + 4);
            bf16x8 f;
            f[0]=(__bf16)a.x; f[1]=(__bf16)a.y; f[2]=(__bf16)a.z; f[3]=(__bf16)a.w;
            f[4]=(__bf16)c.x; f[5]=(__bf16)c.y; f[6]=(__bf16)c.z; f[7]=(__bf16)c.w;
            qf[kh] = f;
        }
    }

    f32x4 acc[4] = {{0,0,0,0},{0,0,0,0},{0,0,0,0},{0,0,0,0}};
    float m_run[4], l_run[4];
    #pragma unroll
    for (int r = 0; r < 4; ++r) { m_run[r] = -INFINITY; l_run[r] = 0.f; }

    const int* maskp = mask + b * SEQ;

    for (int k0 = 0; k0 < SEQ; k0 += KT) {
        #pragma unroll
        for (int i = 0; i < 4; ++i) {
            int e4 = i * 256 + tid;
            int key = e4 >> 4, d4 = (e4 & 15) * 4;
            float4 kv = *(const float4*)(K + base + (size_t)(k0 + key) * HD + d4);
            bf16x4 kb;
            kb[0]=(__bf16)kv.x; kb[1]=(__bf16)kv.y; kb[2]=(__bf16)kv.z; kb[3]=(__bf16)kv.w;
            *(bf16x4*)&Kl[key][d4] = kb;
        }
        #pragma unroll
        for (int i = 0; i < 4; ++i) {
            int e4 = i * 256 + tid;
            int key = e4 >> 4, d4 = (e4 & 15) * 4;
            float4 vv = *(const float4*)(V + base + (size_t)(k0 + key) * HD + d4);
            Vl[d4+0][key] = (__bf16)vv.x;
            Vl[d4+1][key] = (__bf16)vv.y;
            Vl[d4+2][key] = (__bf16)vv.z;
            Vl[d4+3][key] = (__bf16)vv.w;
        }
        __syncthreads();

        float sv[4][4];
        #pragma unroll
        for (int s = 0; s < 4; ++s) {
            f32x4 c = {0,0,0,0};
            bf16x8 kf0 = *(const bf16x8*)&Kl[s*16 + lo][hi*8];
            bf16x8 kf1 = *(const bf16x8*)&Kl[s*16 + lo][32 + hi*8];
            c = __builtin_amdgcn_mfma_f32_16x16x32_bf16(qf[0], kf0, c, 0, 0, 0);
            c = __builtin_amdgcn_mfma_f32_16x16x32_bf16(qf[1], kf1, c, 0, 0, 0);
            const int km = maskp[k0 + s*16 + lo];
            #pragma unroll
            for (int r = 0; r < 4; ++r)
                sv[s][r] = km ? (c[r] * 0.03125f) : -1e9f;
        }

        float tm[4];
        #pragma unroll
        for (int r = 0; r < 4; ++r)
            tm[r] = fmaxf(fmaxf(sv[0][r], sv[1][r]), fmaxf(sv[2][r], sv[3][r]));
        #pragma unroll
        for (int off = 1; off < 16; off <<= 1)
            #pragma unroll
            for (int r = 0; r < 4; ++r)
                tm[r] = fmaxf(tm[r], __shfl_xor(tm[r], off));

        float scl[4];
        #pragma unroll
        for (int r = 0; r < 4; ++r) {
            float mn = fmaxf(m_run[r], tm[r]);
            scl[r] = __expf(m_run[r] - mn);
            m_run[r] = mn;
        }
        float pv_[4][4], rs[4] = {0.f, 0.f, 0.f, 0.f};
        #pragma unroll
        for (int s = 0; s < 4; ++s)
            #pragma unroll
            for (int r = 0; r < 4; ++r) {
                float p = __expf(sv[s][r] - m_run[r]);
                pv_[s][r] = p;
                rs[r] += p;
            }
        #pragma unroll
        for (int off = 1; off < 16; off <<= 1)
            #pragma unroll
            for (int r = 0; r < 4; ++r)
                rs[r] += __shfl_xor(rs[r], off);
        #pragma unroll
        for (int r = 0; r < 4; ++r)
            l_run[r] = l_run[r] * scl[r] + rs[r];
        #pragma unroll
        for (int nt = 0; nt < 4; ++nt)
            #pragma unroll
            for (int r = 0; r < 4; ++r)
                acc[nt][r] *= scl[r];

        #pragma unroll
        for (int s = 0; s < 4; ++s)
            #pragma unroll
            for (int r = 0; r < 4; ++r)
                Pl[w][hi*4 + r][s*16 + lo] = (__bf16)pv_[s][r];

        bf16x8 pa0 = *(const bf16x8*)&Pl[w][lo][hi*8];
        bf16x8 pa1 = *(const bf16x8*)&Pl[w][lo][32 + hi*8];
        #pragma unroll
        for (int nt = 0; nt < 4; ++nt) {
            bf16x8 v0 = *(const bf16x8*)&Vl[nt*16 + lo][hi*8];
            bf16x8 v1 = *(const bf16x8*)&Vl[nt*16 + lo][32 + hi*8];
            acc[nt] = __builtin_amdgcn_mfma_f32_16x16x32_bf16(pa0, v0, acc[nt], 0, 0, 0);
            acc[nt] = __builtin_amdgcn_mfma_f32_16x16x32_bf16(pa1, v1, acc[nt], 0, 0, 0);
        }
        __syncthreads();
    }

    float inv[4];
    #pragma unroll
    for (int r = 0; r < 4; ++r) inv[r] = 1.0f / l_run[r];
    float* op = out + base + (size_t)qbase * HD;
    #pragma unroll
    for (int nt = 0; nt < 4; ++nt)
        #pragma unroll
        for (int r = 0; r < 4; ++r)
            op[(size_t)(hi*4 + r) * HD + nt*16 + lo] = acc[nt][r] * inv[r];
}

extern "C" void kernel_launch(void* const* d_in, const int* in_sizes, int n_in,
                              void* d_out, int out_size, void* d_ws, size_t ws_size,
                              hipStream_t stream) {
    (void)in_sizes; (void)n_in; (void)out_size;
    const float* Q  = (const float*)d_in[0];
    const float* K  = (const float*)d_in[1];
    const float* V  = (const float*)d_in[2];
    const int* mask = (const int*)d_in[3];
    float* out      = (float*)d_out;

    const size_t kv_elems = (size_t)32 * SEQ * HD;          // per tensor
    const size_t need = kv_elems * 2 /*bf16*/ * 2 /*K+V*/;  // 16.78 MB

    if (ws_size >= need) {
        __bf16* Kf = (__bf16*)d_ws;
        __bf16* Vf = Kf + kv_elems;
        hipLaunchKernelGGL(prepass, dim3(NT, 32), dim3(256), 0, stream, K, V, Kf, Vf);
        hipLaunchKernelGGL(attn_fwd3, dim3(1024), dim3(256), 0, stream,
                           Q, Kf, Vf, mask, out);
    } else {
        hipLaunchKernelGGL(attn_fwd_legacy, dim3(SEQ / QB, 32), dim3(256), 0, stream,
                           Q, K, V, mask, out);
    }
}